// Round 8
// baseline (241.684 us; speedup 1.0000x reference)
//
#include <hip/hip_runtime.h>
#include <hip/hip_bf16.h>

// Problem: B=2, S=2048, EMB=1024, H=16, D=64.
// fp32 I/O; bf16 MFMA pipeline. V pre-transposed by QKV GEMM ([B,H,D,S]).
// Q pre-scaled by SCALE*log2(e) so attention softmax runs in exp2 domain.
#define BB   2
#define SS   2048
#define EMBD 1024
#define NH   16
#define HD   64
#define QSCALE 0.18033688011112042f  // 0.125 * log2(e)
#define NEG_BIG (-1e30f)

typedef __bf16 bf16;
typedef float  floatx4 __attribute__((ext_vector_type(4)));
typedef __bf16 bf16x4  __attribute__((ext_vector_type(4)));
typedef __bf16 bf16x8  __attribute__((ext_vector_type(8)));

typedef const __attribute__((address_space(1))) void* gas_ptr;
typedef __attribute__((address_space(3))) void*       las_ptr;

__device__ __forceinline__ void gl_lds16(const void* g, void* l) {
    __builtin_amdgcn_global_load_lds((gas_ptr)g, (las_ptr)l, 16, 0, 0);
}

__device__ __forceinline__ bf16x8 cvt8(const float* p) {
    bf16x8 o;
#pragma unroll
    for (int j = 0; j < 8; j++) o[j] = (bf16)p[j];
    return o;
}

// ---------------------------------------------------------------------------
// fp32 -> bf16 conversion for x tensors (4Mi els each) and W matrices (1Mi).
// ---------------------------------------------------------------------------
__global__ __launch_bounds__(256) void cvt_all(
    const float* __restrict__ xq, const float* __restrict__ xk,
    const float* __restrict__ xv, const float* __restrict__ Wq,
    const float* __restrict__ Wk, const float* __restrict__ Wv,
    const float* __restrict__ Wo, bf16* __restrict__ xqo,
    bf16* __restrict__ xko, bf16* __restrict__ xvo, bf16* __restrict__ Wqo,
    bf16* __restrict__ Wko, bf16* __restrict__ Wvo, bf16* __restrict__ Woo) {
    const int y = blockIdx.y;
    const float* src;
    bf16* dst;
    size_t n;
    const size_t NX = (size_t)BB * SS * EMBD;    // 4 Mi
    const size_t NW = (size_t)EMBD * EMBD;       // 1 Mi
    switch (y) {
        case 0: src = xq; dst = xqo; n = NX; break;
        case 1: src = xk; dst = xko; n = NX; break;
        case 2: src = xv; dst = xvo; n = NX; break;
        case 3: src = Wq; dst = Wqo; n = NW; break;
        case 4: src = Wk; dst = Wko; n = NW; break;
        case 5: src = Wv; dst = Wvo; n = NW; break;
        default: src = Wo; dst = Woo; n = NW; break;
    }
    const size_t stride = (size_t)gridDim.x * blockDim.x * 4;
    for (size_t i = ((size_t)blockIdx.x * blockDim.x + threadIdx.x) * 4;
         i < n; i += stride) {
        floatx4 v = *(const floatx4*)(src + i);
        bf16x4 o = {(bf16)v[0], (bf16)v[1], (bf16)v[2], (bf16)v[3]};
        *(bf16x4*)(dst + i) = o;
    }
}

// ---------------------------------------------------------------------------
// GEMM: out[m][n] = (sum_k A[m][k]*W[n][k] + bias[n]) * oscale
// Tile BM x 128, BM = 32*FM. BK=64 staged as two packed 32-col halves via
// global_load_lds w=16. Epilogue via per-wave LDS repack -> 16B stores.
// MODE 0: bf16 [B,H,S,D].  MODE 1: fp32 [M][N].  MODE 2: bf16 [B,H,D,S]
// (V^T; C^T via swapped MFMA operands).
// __launch_bounds__(256,4) on callers: cap ~128 VGPR -> 4 blocks/CU so the
// per-iter barrier vmcnt drain overlaps across resident blocks.
// ---------------------------------------------------------------------------
template <int MODE, int FM>
__device__ __forceinline__ void gemm_body(const bf16* __restrict__ A,
                                          const bf16* __restrict__ W,
                                          const float* __restrict__ bias,
                                          void* __restrict__ Ov,
                                          int mBase, int nBase, float oscale) {
    constexpr int BM = 32 * FM;
    constexpr int ABYTES = BM * 64 * 2;          // A staging bytes
    constexpr int STG = ABYTES + 128 * 64 * 2;   // + B staging
    constexpr int SMEMSZ = (STG > 17408) ? STG : 17408;
    __shared__ __align__(16) char smem[SMEMSZ];
    bf16* As = (bf16*)smem;
    bf16* Bs = (bf16*)(smem + ABYTES);

    const int t = threadIdx.x;
    const int l = t & 63, w = t >> 6;
    const int lm = l & 15, lq = l >> 4;
    const int K = 1024;
    const int wm = (w >> 1) * (16 * FM), wn = (w & 1) * 64;

    const floatx4 zero = {0.f, 0.f, 0.f, 0.f};
    floatx4 acc[FM][4];
#pragma unroll
    for (int i = 0; i < FM; i++)
#pragma unroll
        for (int j = 0; j < 4; j++) acc[i][j] = zero;

    for (int kb = 0; kb < K; kb += 64) {
        __syncthreads();
        // A: FM passes (chunks per 32-col half = BM*4)
#pragma unroll
        for (int ia = 0; ia < FM; ia++) {
            int half = ia / (FM / 2 > 0 ? FM / 2 : 1);
            int rem  = (ia % (FM / 2 > 0 ? FM / 2 : 1)) * 256 + t;
            int row  = rem >> 2;
            int col  = half * 32 + (rem & 3) * 8;
            gl_lds16(A + (size_t)(mBase + row) * K + kb + col,
                     (char*)As + (ia * 256 + w * 64) * 16);
        }
        // B: 4 passes (BN=128)
#pragma unroll
        for (int i = 0; i < 4; i++) {
            int half = i >> 1;
            int rem  = (i & 1) * 256 + t;
            int row  = rem >> 2;
            int col  = half * 32 + (rem & 3) * 8;
            gl_lds16(W + (size_t)(nBase + row) * K + kb + col,
                     (char*)Bs + (i * 256 + w * 64) * 16);
        }
        __syncthreads();

#pragma unroll
        for (int half = 0; half < 2; half++) {
            const bf16* Ah = As + half * BM * 32;
            const bf16* Bh = Bs + half * 128 * 32;
            bf16x8 af[FM], bfv[4];
#pragma unroll
            for (int f = 0; f < FM; f++)
                af[f] = *(const bf16x8*)&Ah[(wm + f * 16 + lm) * 32 + lq * 8];
#pragma unroll
            for (int f = 0; f < 4; f++)
                bfv[f] = *(const bf16x8*)&Bh[(wn + f * 16 + lm) * 32 + lq * 8];
            if (MODE == 2) {
#pragma unroll
                for (int i = 0; i < 4; i++)
#pragma unroll
                    for (int j = 0; j < FM; j++)
                        acc[j][i] = __builtin_amdgcn_mfma_f32_16x16x32_bf16(
                            bfv[i], af[j], acc[j][i], 0, 0, 0);
            } else {
#pragma unroll
                for (int fm = 0; fm < FM; fm++)
#pragma unroll
                    for (int fn = 0; fn < 4; fn++)
                        acc[fm][fn] =
                            __builtin_amdgcn_mfma_f32_16x16x32_bf16(
                                af[fm], bfv[fn], acc[fm][fn], 0, 0, 0);
            }
        }
    }

    // ---- Epilogue via per-wave LDS repack (stride 68 f32) ----
    __syncthreads();
    float* rp = (float*)smem + w * (16 * 68);

    if (MODE != 2) {
        float bvv[4];
#pragma unroll
        for (int fn = 0; fn < 4; fn++)
            bvv[fn] = bias[nBase + wn + fn * 16 + lm];
#pragma unroll
        for (int fm = 0; fm < FM; fm++) {
#pragma unroll
            for (int fn = 0; fn < 4; fn++)
#pragma unroll
                for (int r = 0; r < 4; r++)
                    rp[(lq * 4 + r) * 68 + fn * 16 + lm] =
                        (acc[fm][fn][r] + bvv[fn]) * oscale;
            if (MODE == 0) {
                int row2 = l >> 3, col8 = l & 7;
                int h = (nBase + wn) >> 6;
#pragma unroll
                for (int p = 0; p < 2; p++) {
                    int row = p * 8 + row2;
                    int m = mBase + wm + fm * 16 + row;
                    int b = m >> 11, s = m & 2047;
                    bf16x8 o = cvt8(&rp[row * 68 + col8 * 8]);
                    *(bf16x8*)((bf16*)Ov +
                               (((size_t)(b * NH + h)) * SS + s) * HD +
                               col8 * 8) = o;
                }
            } else {
                int c4 = l & 15;
#pragma unroll
                for (int p = 0; p < 4; p++) {
                    int row = p * 4 + (l >> 4);
                    int m = mBase + wm + fm * 16 + row;
                    floatx4 o = *(const floatx4*)&rp[row * 68 + c4 * 4];
                    *(floatx4*)((float*)Ov + (size_t)m * EMBD + nBase + wn +
                                c4 * 4) = o;
                }
            }
        }
    } else {
        const int b = (mBase + wm) >> 11;
        const int sbase = (mBase + wm) & 2047;
#pragma unroll
        for (int i = 0; i < 4; i++) {
            float bv[4];
#pragma unroll
            for (int r = 0; r < 4; r++)
                bv[r] = bias[nBase + wn + i * 16 + lq * 4 + r];
#pragma unroll
            for (int j = 0; j < FM; j++)
#pragma unroll
                for (int r = 0; r < 4; r++)
                    rp[(lq * 4 + r) * 68 + j * 16 + lm] =
                        acc[j][i][r] + bv[r];
            int row2 = l >> 3, col8 = l & 7;
#pragma unroll
            for (int p = 0; p < 2; p++) {
                int row = p * 8 + row2;
                int n = nBase + wn + i * 16 + row;
                int h = n >> 6, d = n & 63;
                bf16x8 o = cvt8(&rp[row * 68 + col8 * 8]);
                *(bf16x8*)((bf16*)Ov +
                           ((size_t)(b * NH + h) * HD + d) * SS + sbase +
                           col8 * 8) = o;
            }
        }
    }
}

__global__ __launch_bounds__(256, 4) void gemm_qkv(
    const bf16* __restrict__ xq, const bf16* __restrict__ xk,
    const bf16* __restrict__ xv, const bf16* __restrict__ Wq,
    const bf16* __restrict__ Wk, const bf16* __restrict__ Wv,
    const float* __restrict__ bq, const float* __restrict__ bk,
    const float* __restrict__ bv, bf16* __restrict__ Qo,
    bf16* __restrict__ Ko, bf16* __restrict__ Vo) {
    const int z = blockIdx.z;
    if (z == 0)  // Q pre-scaled for exp2-domain softmax
        gemm_body<0, 4>(xq, Wq, bq, Qo, blockIdx.y * 128, blockIdx.x * 128,
                        QSCALE);
    else if (z == 1)
        gemm_body<0, 4>(xk, Wk, bk, Ko, blockIdx.y * 128, blockIdx.x * 128,
                        1.0f);
    else
        gemm_body<2, 4>(xv, Wv, bv, Vo, blockIdx.y * 128, blockIdx.x * 128,
                        1.0f);
}

__global__ __launch_bounds__(256, 4) void gemm_out(
    const bf16* __restrict__ A, const bf16* __restrict__ W,
    const float* __restrict__ bias, float* __restrict__ O) {
    gemm_body<1, 2>(A, W, bias, O, blockIdx.y * 64, blockIdx.x * 128, 1.0f);
}

// ---------------------------------------------------------------------------
// Flash attention (unchanged from R7). Q(pre-scaled),K in [B,H,S,D]; V^T in
// [B,H,D,S]; bf16. Grid 1024 blocks, one q-tile each, longest-first,
// XCD-pinned. exp2-domain softmax. 4 blocks/CU.
// ---------------------------------------------------------------------------
__global__ __launch_bounds__(256, 4) void attn_fwd(
    const bf16* __restrict__ Qg, const bf16* __restrict__ Kg,
    const bf16* __restrict__ Vtg, bf16* __restrict__ Oatt) {
    __shared__ __align__(16) bf16 Ks[64 * 72];
    __shared__ __align__(16) bf16 VT[64 * 72];
    __shared__ __align__(16) bf16 Ps[4][16 * 72];

    const int t = threadIdx.x;
    const int l = t & 63, w = t >> 6;
    const int lm = l & 15, lq = l >> 4;
    const int x = blockIdx.x;
    const int qt = 31 - (x >> 5);
    const int bh = (((x >> 3) & 3) << 3) | (x & 7);
    const size_t kbase = (size_t)bh * SS * HD;
    const size_t vbase = (size_t)bh * HD * SS;
    const int b = bh >> 4, h = bh & 15;
    const floatx4 zero = {0.f, 0.f, 0.f, 0.f};

    bf16x8 qa0, qa1;
    {
        const bf16* qp =
            Qg + kbase + (size_t)(qt * 64 + w * 16 + lm) * HD + lq * 8;
        qa0 = *(const bf16x8*)qp;
        qa1 = *(const bf16x8*)(qp + 32);
    }

    float m_i = NEG_BIG, l_i = 0.f;
    floatx4 od[4];
#pragma unroll
    for (int dt = 0; dt < 4; dt++) od[dt] = zero;

    const int qglob = qt * 64 + w * 16 + lm;

    bf16x8 kreg[2], vreg[2];
#pragma unroll
    for (int i = 0; i < 2; i++) {
        int idx = i * 256 + t;
        int row = idx >> 3;
        int col = (idx & 7) * 8;
        kreg[i] = *(const bf16x8*)(Kg + kbase + (size_t)row * HD + col);
        vreg[i] = *(const bf16x8*)(Vtg + vbase + (size_t)row * SS + col);
    }

    for (int kt = 0; kt <= qt; ++kt) {
        __syncthreads();
#pragma unroll
        for (int i = 0; i < 2; i++) {
            int idx = i * 256 + t;
            int row = idx >> 3;
            int col = (idx & 7) * 8;
            *(bf16x8*)&Ks[row * 72 + col] = kreg[i];
            *(bf16x8*)&VT[row * 72 + col] = vreg[i];
        }
        __syncthreads();
        if (kt < qt) {
#pragma unroll
            for (int i = 0; i < 2; i++) {
                int idx = i * 256 + t;
                int row = idx >> 3;
                int col = (idx & 7) * 8;
                kreg[i] = *(const bf16x8*)(
                    Kg + kbase + (size_t)((kt + 1) * 64 + row) * HD + col);
                vreg[i] = *(const bf16x8*)(
                    Vtg + vbase + (size_t)row * SS + (kt + 1) * 64 + col);
            }
        }

        floatx4 sc[4];
#pragma unroll
        for (int j0 = 0; j0 < 4; j0++) {
            int rowK = j0 * 16 + lm;
            bf16x8 k0 = *(const bf16x8*)&Ks[rowK * 72 + lq * 8];
            bf16x8 k1 = *(const bf16x8*)&Ks[rowK * 72 + 32 + lq * 8];
            floatx4 z = zero;
            z = __builtin_amdgcn_mfma_f32_16x16x32_bf16(k0, qa0, z, 0, 0, 0);
            z = __builtin_amdgcn_mfma_f32_16x16x32_bf16(k1, qa1, z, 0, 0, 0);
            sc[j0] = z;
        }
        if (kt == qt) {
#pragma unroll
            for (int j0 = 0; j0 < 4; j0++)
#pragma unroll
                for (int r = 0; r < 4; r++) {
                    int key = kt * 64 + j0 * 16 + lq * 4 + r;
                    if (key > qglob) sc[j0][r] = NEG_BIG;
                }
        }
        float mt = sc[0][0];
#pragma unroll
        for (int j0 = 0; j0 < 4; j0++)
#pragma unroll
            for (int r = 0; r < 4; r++) mt = fmaxf(mt, sc[j0][r]);
        mt = fmaxf(mt, __shfl_xor(mt, 16));
        mt = fmaxf(mt, __shfl_xor(mt, 32));
        float mnew = fmaxf(m_i, mt);
        float alpha = exp2f(m_i - mnew);
        m_i = mnew;
        float ps = 0.f;
#pragma unroll
        for (int j0 = 0; j0 < 4; j0++)
#pragma unroll
            for (int r = 0; r < 4; r++) {
                float p = exp2f(sc[j0][r] - mnew);
                sc[j0][r] = p;
                ps += p;
            }
        ps += __shfl_xor(ps, 16);
        ps += __shfl_xor(ps, 32);
        l_i = l_i * alpha + ps;
#pragma unroll
        for (int j0 = 0; j0 < 4; j0++) {
            bf16x4 pk = {(bf16)sc[j0][0], (bf16)sc[j0][1], (bf16)sc[j0][2],
                         (bf16)sc[j0][3]};
            *(bf16x4*)&Ps[w][lm * 72 + j0 * 16 + lq * 4] = pk;
        }
        float a0 = __shfl(alpha, lq * 4 + 0);
        float a1 = __shfl(alpha, lq * 4 + 1);
        float a2 = __shfl(alpha, lq * 4 + 2);
        float a3 = __shfl(alpha, lq * 4 + 3);
#pragma unroll
        for (int dt = 0; dt < 4; dt++) {
            od[dt][0] *= a0;
            od[dt][1] *= a1;
            od[dt][2] *= a2;
            od[dt][3] *= a3;
        }
        bf16x8 pa0 = *(const bf16x8*)&Ps[w][lm * 72 + lq * 8];
        bf16x8 pa1 = *(const bf16x8*)&Ps[w][lm * 72 + 32 + lq * 8];
#pragma unroll
        for (int dt = 0; dt < 4; dt++) {
            int rowD = dt * 16 + lm;
            bf16x8 v0 = *(const bf16x8*)&VT[rowD * 72 + lq * 8];
            bf16x8 v1 = *(const bf16x8*)&VT[rowD * 72 + 32 + lq * 8];
            od[dt] = __builtin_amdgcn_mfma_f32_16x16x32_bf16(pa0, v0, od[dt],
                                                             0, 0, 0);
            od[dt] = __builtin_amdgcn_mfma_f32_16x16x32_bf16(pa1, v1, od[dt],
                                                             0, 0, 0);
        }
    }

    float lr0 = __shfl(l_i, lq * 4 + 0);
    float lr1 = __shfl(l_i, lq * 4 + 1);
    float lr2 = __shfl(l_i, lq * 4 + 2);
    float lr3 = __shfl(l_i, lq * 4 + 3);
    float lr[4] = {lr0, lr1, lr2, lr3};
#pragma unroll
    for (int dt = 0; dt < 4; dt++) {
#pragma unroll
        for (int r = 0; r < 4; r++) {
            int s = qt * 64 + w * 16 + lq * 4 + r;
            float v = od[dt][r] / lr[r];
            Oatt[((size_t)(b * SS + s)) * EMBD + h * HD + dt * 16 + lm] =
                (bf16)v;
        }
    }
}

// ---------------------------------------------------------------------------
extern "C" void kernel_launch(void* const* d_in, const int* in_sizes, int n_in,
                              void* d_out, int out_size, void* d_ws,
                              size_t ws_size, hipStream_t stream) {
    const float* xq = (const float*)d_in[0];
    const float* xk = (const float*)d_in[1];
    const float* xv = (const float*)d_in[2];
    // d_in[3] = causal mask — hard-coded
    const float* Wq = (const float*)d_in[4];
    const float* bq = (const float*)d_in[5];
    const float* Wk = (const float*)d_in[6];
    const float* bk = (const float*)d_in[7];
    const float* Wv = (const float*)d_in[8];
    const float* bv = (const float*)d_in[9];
    const float* Wo = (const float*)d_in[10];
    const float* bo = (const float*)d_in[11];
    float* out = (float*)d_out;

    const size_t NX = (size_t)BB * SS * EMBD;
    const size_t NW = (size_t)EMBD * EMBD;
    bf16* Qw  = (bf16*)d_ws;        // [B,H,S,D], pre-scaled
    bf16* Kw  = Qw + NX;            // [B,H,S,D]
    bf16* Vw  = Kw + NX;            // [B,H,D,S]
    bf16* Aw  = Vw + NX;            // [B,S,E]
    bf16* xqb = Aw + NX;
    bf16* xkb = xqb + NX;
    bf16* xvb = xkb + NX;
    bf16* Wqb = xvb + NX;
    bf16* Wkb = Wqb + NW;
    bf16* Wvb = Wkb + NW;
    bf16* Wob = Wvb + NW;

    cvt_all<<<dim3(1024, 7), 256, 0, stream>>>(xq, xk, xv, Wq, Wk, Wv, Wo,
                                               xqb, xkb, xvb, Wqb, Wkb, Wvb,
                                               Wob);
    gemm_qkv<<<dim3(8, 32, 3), 256, 0, stream>>>(xqb, xkb, xvb, Wqb, Wkb, Wvb,
                                                 bq, bk, bv, Qw, Kw, Vw);
    attn_fwd<<<dim3(1024), 256, 0, stream>>>(Qw, Kw, Vw, Aw);
    gemm_out<<<dim3(8, 64), 256, 0, stream>>>(Aw, Wob, bo, out);
}

// Round 9
// 229.701 us; speedup vs baseline: 1.0522x; 1.0522x over previous
//
#include <hip/hip_runtime.h>
#include <hip/hip_bf16.h>

// Problem: B=2, S=2048, EMB=1024, H=16, D=64.
// fp32 I/O; bf16 MFMA pipeline. V pre-transposed by QKV GEMM ([B,H,D,S]).
// Q pre-scaled by SCALE*log2(e) so attention softmax runs in exp2 domain.
#define BB   2
#define SS   2048
#define EMBD 1024
#define NH   16
#define HD   64
#define QSCALE 0.18033688011112042f  // 0.125 * log2(e)
#define NEG_BIG (-1e30f)

typedef __bf16 bf16;
typedef float  floatx4 __attribute__((ext_vector_type(4)));
typedef __bf16 bf16x4  __attribute__((ext_vector_type(4)));
typedef __bf16 bf16x8  __attribute__((ext_vector_type(8)));

typedef const __attribute__((address_space(1))) void* gas_ptr;
typedef __attribute__((address_space(3))) void*       las_ptr;

__device__ __forceinline__ void gl_lds16(const void* g, void* l) {
    __builtin_amdgcn_global_load_lds((gas_ptr)g, (las_ptr)l, 16, 0, 0);
}

__device__ __forceinline__ bf16x8 cvt8(const float* p) {
    bf16x8 o;
#pragma unroll
    for (int j = 0; j < 8; j++) o[j] = (bf16)p[j];
    return o;
}

// ---------------------------------------------------------------------------
// fp32 -> bf16 conversion for x tensors (4Mi els each) and W matrices (1Mi).
// ---------------------------------------------------------------------------
__global__ __launch_bounds__(256) void cvt_all(
    const float* __restrict__ xq, const float* __restrict__ xk,
    const float* __restrict__ xv, const float* __restrict__ Wq,
    const float* __restrict__ Wk, const float* __restrict__ Wv,
    const float* __restrict__ Wo, bf16* __restrict__ xqo,
    bf16* __restrict__ xko, bf16* __restrict__ xvo, bf16* __restrict__ Wqo,
    bf16* __restrict__ Wko, bf16* __restrict__ Wvo, bf16* __restrict__ Woo) {
    const int y = blockIdx.y;
    const float* src;
    bf16* dst;
    size_t n;
    const size_t NX = (size_t)BB * SS * EMBD;    // 4 Mi
    const size_t NW = (size_t)EMBD * EMBD;       // 1 Mi
    switch (y) {
        case 0: src = xq; dst = xqo; n = NX; break;
        case 1: src = xk; dst = xko; n = NX; break;
        case 2: src = xv; dst = xvo; n = NX; break;
        case 3: src = Wq; dst = Wqo; n = NW; break;
        case 4: src = Wk; dst = Wko; n = NW; break;
        case 5: src = Wv; dst = Wvo; n = NW; break;
        default: src = Wo; dst = Woo; n = NW; break;
    }
    const size_t stride = (size_t)gridDim.x * blockDim.x * 4;
    for (size_t i = ((size_t)blockIdx.x * blockDim.x + threadIdx.x) * 4;
         i < n; i += stride) {
        floatx4 v = *(const floatx4*)(src + i);
        bf16x4 o = {(bf16)v[0], (bf16)v[1], (bf16)v[2], (bf16)v[3]};
        *(bf16x4*)(dst + i) = o;
    }
}

// ---------------------------------------------------------------------------
// GEMM: out[m][n] = (sum_k A[m][k]*W[n][k] + bias[n]) * oscale
// Tile BM x 128, BM = 32*FM. BK=64 staged as two packed 32-col halves via
// global_load_lds w=16. Epilogue via per-wave LDS repack -> 16B stores.
// LDS is DYNAMIC (extern __shared__) so multiple template instantiations in
// one kernel share a single allocation (R8's dual static arrays -> 64 KB
// LDS -> 2 blocks/CU was the occupancy killer).
// MODE 0: bf16 [B,H,S,D].  MODE 1: fp32 [M][N].  MODE 2: bf16 [B,H,D,S].
// ---------------------------------------------------------------------------
extern __shared__ __align__(16) char smem[];

template <int MODE, int FM>
__device__ __forceinline__ void gemm_body(const bf16* __restrict__ A,
                                          const bf16* __restrict__ W,
                                          const float* __restrict__ bias,
                                          void* __restrict__ Ov,
                                          int mBase, int nBase, float oscale) {
    constexpr int BM = 32 * FM;
    constexpr int ABYTES = BM * 64 * 2;          // A staging bytes
    bf16* As = (bf16*)smem;
    bf16* Bs = (bf16*)(smem + ABYTES);

    const int t = threadIdx.x;
    const int l = t & 63, w = t >> 6;
    const int lm = l & 15, lq = l >> 4;
    const int K = 1024;
    const int wm = (w >> 1) * (16 * FM), wn = (w & 1) * 64;

    const floatx4 zero = {0.f, 0.f, 0.f, 0.f};
    floatx4 acc[FM][4];
#pragma unroll
    for (int i = 0; i < FM; i++)
#pragma unroll
        for (int j = 0; j < 4; j++) acc[i][j] = zero;

    for (int kb = 0; kb < K; kb += 64) {
        __syncthreads();
        // A: FM passes (chunks per 32-col half = BM*4)
#pragma unroll
        for (int ia = 0; ia < FM; ia++) {
            int half = ia / (FM / 2 > 0 ? FM / 2 : 1);
            int rem  = (ia % (FM / 2 > 0 ? FM / 2 : 1)) * 256 + t;
            int row  = rem >> 2;
            int col  = half * 32 + (rem & 3) * 8;
            gl_lds16(A + (size_t)(mBase + row) * K + kb + col,
                     (char*)As + (ia * 256 + w * 64) * 16);
        }
        // B: 4 passes (BN=128)
#pragma unroll
        for (int i = 0; i < 4; i++) {
            int half = i >> 1;
            int rem  = (i & 1) * 256 + t;
            int row  = rem >> 2;
            int col  = half * 32 + (rem & 3) * 8;
            gl_lds16(W + (size_t)(nBase + row) * K + kb + col,
                     (char*)Bs + (i * 256 + w * 64) * 16);
        }
        __syncthreads();

#pragma unroll
        for (int half = 0; half < 2; half++) {
            const bf16* Ah = As + half * BM * 32;
            const bf16* Bh = Bs + half * 128 * 32;
            bf16x8 af[FM], bfv[4];
#pragma unroll
            for (int f = 0; f < FM; f++)
                af[f] = *(const bf16x8*)&Ah[(wm + f * 16 + lm) * 32 + lq * 8];
#pragma unroll
            for (int f = 0; f < 4; f++)
                bfv[f] = *(const bf16x8*)&Bh[(wn + f * 16 + lm) * 32 + lq * 8];
            if (MODE == 2) {
#pragma unroll
                for (int i = 0; i < 4; i++)
#pragma unroll
                    for (int j = 0; j < FM; j++)
                        acc[j][i] = __builtin_amdgcn_mfma_f32_16x16x32_bf16(
                            bfv[i], af[j], acc[j][i], 0, 0, 0);
            } else {
#pragma unroll
                for (int fm = 0; fm < FM; fm++)
#pragma unroll
                    for (int fn = 0; fn < 4; fn++)
                        acc[fm][fn] =
                            __builtin_amdgcn_mfma_f32_16x16x32_bf16(
                                af[fm], bfv[fn], acc[fm][fn], 0, 0, 0);
            }
        }
    }

    // ---- Epilogue via per-wave LDS repack (stride 68 f32) ----
    __syncthreads();
    float* rp = (float*)smem + w * (16 * 68);

    if (MODE != 2) {
        float bvv[4];
#pragma unroll
        for (int fn = 0; fn < 4; fn++)
            bvv[fn] = bias[nBase + wn + fn * 16 + lm];
#pragma unroll
        for (int fm = 0; fm < FM; fm++) {
#pragma unroll
            for (int fn = 0; fn < 4; fn++)
#pragma unroll
                for (int r = 0; r < 4; r++)
                    rp[(lq * 4 + r) * 68 + fn * 16 + lm] =
                        (acc[fm][fn][r] + bvv[fn]) * oscale;
            if (MODE == 0) {
                int row2 = l >> 3, col8 = l & 7;
                int h = (nBase + wn) >> 6;
#pragma unroll
                for (int p = 0; p < 2; p++) {
                    int row = p * 8 + row2;
                    int m = mBase + wm + fm * 16 + row;
                    int b = m >> 11, s = m & 2047;
                    bf16x8 o = cvt8(&rp[row * 68 + col8 * 8]);
                    *(bf16x8*)((bf16*)Ov +
                               (((size_t)(b * NH + h)) * SS + s) * HD +
                               col8 * 8) = o;
                }
            } else {
                int c4 = l & 15;
#pragma unroll
                for (int p = 0; p < 4; p++) {
                    int row = p * 4 + (l >> 4);
                    int m = mBase + wm + fm * 16 + row;
                    floatx4 o = *(const floatx4*)&rp[row * 68 + c4 * 4];
                    *(floatx4*)((float*)Ov + (size_t)m * EMBD + nBase + wn +
                                c4 * 4) = o;
                }
            }
        }
    } else {
        const int b = (mBase + wm) >> 11;
        const int sbase = (mBase + wm) & 2047;
#pragma unroll
        for (int i = 0; i < 4; i++) {
            float bv[4];
#pragma unroll
            for (int r = 0; r < 4; r++)
                bv[r] = bias[nBase + wn + i * 16 + lq * 4 + r];
#pragma unroll
            for (int j = 0; j < FM; j++)
#pragma unroll
                for (int r = 0; r < 4; r++)
                    rp[(lq * 4 + r) * 68 + j * 16 + lm] =
                        acc[j][i][r] + bv[r];
            int row2 = l >> 3, col8 = l & 7;
#pragma unroll
            for (int p = 0; p < 2; p++) {
                int row = p * 8 + row2;
                int n = nBase + wn + i * 16 + row;
                int h = n >> 6, d = n & 63;
                bf16x8 o = cvt8(&rp[row * 68 + col8 * 8]);
                *(bf16x8*)((bf16*)Ov +
                           ((size_t)(b * NH + h) * HD + d) * SS + sbase +
                           col8 * 8) = o;
            }
        }
    }
}

// grid (32, 8, 3): flat%8 = m-tile&7 -> each XCD keeps 4 A-tiles hot in L2
// and re-reads only the small W (2 MB, L2-resident).
__global__ __launch_bounds__(256, 4) void gemm_qkv(
    const bf16* __restrict__ xq, const bf16* __restrict__ xk,
    const bf16* __restrict__ xv, const bf16* __restrict__ Wq,
    const bf16* __restrict__ Wk, const bf16* __restrict__ Wv,
    const float* __restrict__ bq, const float* __restrict__ bk,
    const float* __restrict__ bv, bf16* __restrict__ Qo,
    bf16* __restrict__ Ko, bf16* __restrict__ Vo) {
    const int z = blockIdx.z;
    const int mB = blockIdx.x * 128, nB = blockIdx.y * 128;
    if (z == 0)  // Q pre-scaled for exp2-domain softmax
        gemm_body<0, 4>(xq, Wq, bq, Qo, mB, nB, QSCALE);
    else if (z == 1)
        gemm_body<0, 4>(xk, Wk, bk, Ko, mB, nB, 1.0f);
    else
        gemm_body<2, 4>(xv, Wv, bv, Vo, mB, nB, 1.0f);
}

// grid (64, 8): flat%8 = m-tile&7 (same L2 argument).
__global__ __launch_bounds__(256, 4) void gemm_out(
    const bf16* __restrict__ A, const bf16* __restrict__ W,
    const float* __restrict__ bias, float* __restrict__ O) {
    gemm_body<1, 2>(A, W, bias, O, blockIdx.x * 64, blockIdx.y * 128, 1.0f);
}

// ---------------------------------------------------------------------------
// Flash attention (unchanged from R7). Q(pre-scaled),K in [B,H,S,D]; V^T in
// [B,H,D,S]; bf16. Grid 1024 blocks, one q-tile each, longest-first,
// XCD-pinned. exp2-domain softmax. 4 blocks/CU.
// ---------------------------------------------------------------------------
__global__ __launch_bounds__(256, 4) void attn_fwd(
    const bf16* __restrict__ Qg, const bf16* __restrict__ Kg,
    const bf16* __restrict__ Vtg, bf16* __restrict__ Oatt) {
    __shared__ __align__(16) bf16 Ks[64 * 72];
    __shared__ __align__(16) bf16 VT[64 * 72];
    __shared__ __align__(16) bf16 Ps[4][16 * 72];

    const int t = threadIdx.x;
    const int l = t & 63, w = t >> 6;
    const int lm = l & 15, lq = l >> 4;
    const int x = blockIdx.x;
    const int qt = 31 - (x >> 5);
    const int bh = (((x >> 3) & 3) << 3) | (x & 7);
    const size_t kbase = (size_t)bh * SS * HD;
    const size_t vbase = (size_t)bh * HD * SS;
    const int b = bh >> 4, h = bh & 15;
    const floatx4 zero = {0.f, 0.f, 0.f, 0.f};

    bf16x8 qa0, qa1;
    {
        const bf16* qp =
            Qg + kbase + (size_t)(qt * 64 + w * 16 + lm) * HD + lq * 8;
        qa0 = *(const bf16x8*)qp;
        qa1 = *(const bf16x8*)(qp + 32);
    }

    float m_i = NEG_BIG, l_i = 0.f;
    floatx4 od[4];
#pragma unroll
    for (int dt = 0; dt < 4; dt++) od[dt] = zero;

    const int qglob = qt * 64 + w * 16 + lm;

    bf16x8 kreg[2], vreg[2];
#pragma unroll
    for (int i = 0; i < 2; i++) {
        int idx = i * 256 + t;
        int row = idx >> 3;
        int col = (idx & 7) * 8;
        kreg[i] = *(const bf16x8*)(Kg + kbase + (size_t)row * HD + col);
        vreg[i] = *(const bf16x8*)(Vtg + vbase + (size_t)row * SS + col);
    }

    for (int kt = 0; kt <= qt; ++kt) {
        __syncthreads();
#pragma unroll
        for (int i = 0; i < 2; i++) {
            int idx = i * 256 + t;
            int row = idx >> 3;
            int col = (idx & 7) * 8;
            *(bf16x8*)&Ks[row * 72 + col] = kreg[i];
            *(bf16x8*)&VT[row * 72 + col] = vreg[i];
        }
        __syncthreads();
        if (kt < qt) {
#pragma unroll
            for (int i = 0; i < 2; i++) {
                int idx = i * 256 + t;
                int row = idx >> 3;
                int col = (idx & 7) * 8;
                kreg[i] = *(const bf16x8*)(
                    Kg + kbase + (size_t)((kt + 1) * 64 + row) * HD + col);
                vreg[i] = *(const bf16x8*)(
                    Vtg + vbase + (size_t)row * SS + (kt + 1) * 64 + col);
            }
        }

        floatx4 sc[4];
#pragma unroll
        for (int j0 = 0; j0 < 4; j0++) {
            int rowK = j0 * 16 + lm;
            bf16x8 k0 = *(const bf16x8*)&Ks[rowK * 72 + lq * 8];
            bf16x8 k1 = *(const bf16x8*)&Ks[rowK * 72 + 32 + lq * 8];
            floatx4 z = zero;
            z = __builtin_amdgcn_mfma_f32_16x16x32_bf16(k0, qa0, z, 0, 0, 0);
            z = __builtin_amdgcn_mfma_f32_16x16x32_bf16(k1, qa1, z, 0, 0, 0);
            sc[j0] = z;
        }
        if (kt == qt) {
#pragma unroll
            for (int j0 = 0; j0 < 4; j0++)
#pragma unroll
                for (int r = 0; r < 4; r++) {
                    int key = kt * 64 + j0 * 16 + lq * 4 + r;
                    if (key > qglob) sc[j0][r] = NEG_BIG;
                }
        }
        float mt = sc[0][0];
#pragma unroll
        for (int j0 = 0; j0 < 4; j0++)
#pragma unroll
            for (int r = 0; r < 4; r++) mt = fmaxf(mt, sc[j0][r]);
        mt = fmaxf(mt, __shfl_xor(mt, 16));
        mt = fmaxf(mt, __shfl_xor(mt, 32));
        float mnew = fmaxf(m_i, mt);
        float alpha = exp2f(m_i - mnew);
        m_i = mnew;
        float ps = 0.f;
#pragma unroll
        for (int j0 = 0; j0 < 4; j0++)
#pragma unroll
            for (int r = 0; r < 4; r++) {
                float p = exp2f(sc[j0][r] - mnew);
                sc[j0][r] = p;
                ps += p;
            }
        ps += __shfl_xor(ps, 16);
        ps += __shfl_xor(ps, 32);
        l_i = l_i * alpha + ps;
#pragma unroll
        for (int j0 = 0; j0 < 4; j0++) {
            bf16x4 pk = {(bf16)sc[j0][0], (bf16)sc[j0][1], (bf16)sc[j0][2],
                         (bf16)sc[j0][3]};
            *(bf16x4*)&Ps[w][lm * 72 + j0 * 16 + lq * 4] = pk;
        }
        float a0 = __shfl(alpha, lq * 4 + 0);
        float a1 = __shfl(alpha, lq * 4 + 1);
        float a2 = __shfl(alpha, lq * 4 + 2);
        float a3 = __shfl(alpha, lq * 4 + 3);
#pragma unroll
        for (int dt = 0; dt < 4; dt++) {
            od[dt][0] *= a0;
            od[dt][1] *= a1;
            od[dt][2] *= a2;
            od[dt][3] *= a3;
        }
        bf16x8 pa0 = *(const bf16x8*)&Ps[w][lm * 72 + lq * 8];
        bf16x8 pa1 = *(const bf16x8*)&Ps[w][lm * 72 + 32 + lq * 8];
#pragma unroll
        for (int dt = 0; dt < 4; dt++) {
            int rowD = dt * 16 + lm;
            bf16x8 v0 = *(const bf16x8*)&VT[rowD * 72 + lq * 8];
            bf16x8 v1 = *(const bf16x8*)&VT[rowD * 72 + 32 + lq * 8];
            od[dt] = __builtin_amdgcn_mfma_f32_16x16x32_bf16(pa0, v0, od[dt],
                                                             0, 0, 0);
            od[dt] = __builtin_amdgcn_mfma_f32_16x16x32_bf16(pa1, v1, od[dt],
                                                             0, 0, 0);
        }
    }

    float lr0 = __shfl(l_i, lq * 4 + 0);
    float lr1 = __shfl(l_i, lq * 4 + 1);
    float lr2 = __shfl(l_i, lq * 4 + 2);
    float lr3 = __shfl(l_i, lq * 4 + 3);
    float lr[4] = {lr0, lr1, lr2, lr3};
#pragma unroll
    for (int dt = 0; dt < 4; dt++) {
#pragma unroll
        for (int r = 0; r < 4; r++) {
            int s = qt * 64 + w * 16 + lq * 4 + r;
            float v = od[dt][r] / lr[r];
            Oatt[((size_t)(b * SS + s)) * EMBD + h * HD + dt * 16 + lm] =
                (bf16)v;
        }
    }
}

// ---------------------------------------------------------------------------
extern "C" void kernel_launch(void* const* d_in, const int* in_sizes, int n_in,
                              void* d_out, int out_size, void* d_ws,
                              size_t ws_size, hipStream_t stream) {
    const float* xq = (const float*)d_in[0];
    const float* xk = (const float*)d_in[1];
    const float* xv = (const float*)d_in[2];
    // d_in[3] = causal mask — hard-coded
    const float* Wq = (const float*)d_in[4];
    const float* bq = (const float*)d_in[5];
    const float* Wk = (const float*)d_in[6];
    const float* bk = (const float*)d_in[7];
    const float* Wv = (const float*)d_in[8];
    const float* bv = (const float*)d_in[9];
    const float* Wo = (const float*)d_in[10];
    const float* bo = (const float*)d_in[11];
    float* out = (float*)d_out;

    const size_t NX = (size_t)BB * SS * EMBD;
    const size_t NW = (size_t)EMBD * EMBD;
    bf16* Qw  = (bf16*)d_ws;        // [B,H,S,D], pre-scaled
    bf16* Kw  = Qw + NX;            // [B,H,S,D]
    bf16* Vw  = Kw + NX;            // [B,H,D,S]
    bf16* Aw  = Vw + NX;            // [B,S,E]
    bf16* xqb = Aw + NX;
    bf16* xkb = xqb + NX;
    bf16* xvb = xkb + NX;
    bf16* Wqb = xvb + NX;
    bf16* Wkb = Wqb + NW;
    bf16* Wvb = Wkb + NW;
    bf16* Wob = Wvb + NW;

    cvt_all<<<dim3(1024, 7), 256, 0, stream>>>(xq, xk, xv, Wq, Wk, Wv, Wo,
                                               xqb, xkb, xvb, Wqb, Wkb, Wvb,
                                               Wob);
    // dynamic LDS: 32 KB (A 16 KB + B 16 KB; epilogue repack fits inside)
    gemm_qkv<<<dim3(32, 8, 3), 256, 32768, stream>>>(
        xqb, xkb, xvb, Wqb, Wkb, Wvb, bq, bk, bv, Qw, Kw, Vw);
    attn_fwd<<<dim3(1024), 256, 0, stream>>>(Qw, Kw, Vw, Aw);
    // dynamic LDS: A 8 KB + B 16 KB = 24 KB (>= 17408 repack)
    gemm_out<<<dim3(64, 8), 256, 24576, stream>>>(Aw, Wob, bo, out);
}

// Round 10
// 224.995 us; speedup vs baseline: 1.0742x; 1.0209x over previous
//
#include <hip/hip_runtime.h>
#include <hip/hip_bf16.h>

// Problem: B=2, S=2048, EMB=1024, H=16, D=64.
// fp32 I/O; bf16 MFMA pipeline. V pre-transposed by QKV GEMM ([B,H,D,S]).
// Q pre-scaled by SCALE*log2(e) so attention softmax runs in exp2 domain.
#define BB   2
#define SS   2048
#define EMBD 1024
#define NH   16
#define HD   64
#define QSCALE 0.18033688011112042f  // 0.125 * log2(e)
#define NEG_BIG (-1e30f)

typedef __bf16 bf16;
typedef float  floatx4 __attribute__((ext_vector_type(4)));
typedef __bf16 bf16x4  __attribute__((ext_vector_type(4)));
typedef __bf16 bf16x8  __attribute__((ext_vector_type(8)));

typedef const __attribute__((address_space(1))) void* gas_ptr;
typedef __attribute__((address_space(3))) void*       las_ptr;

__device__ __forceinline__ void gl_lds16(const void* g, void* l) {
    __builtin_amdgcn_global_load_lds((gas_ptr)g, (las_ptr)l, 16, 0, 0);
}

__device__ __forceinline__ bf16x8 cvt8(const float* p) {
    bf16x8 o;
#pragma unroll
    for (int j = 0; j < 8; j++) o[j] = (bf16)p[j];
    return o;
}

// ---------------------------------------------------------------------------
// fp32 -> bf16 conversion for x tensors (4Mi els each) and W matrices (1Mi).
// ---------------------------------------------------------------------------
__global__ __launch_bounds__(256) void cvt_all(
    const float* __restrict__ xq, const float* __restrict__ xk,
    const float* __restrict__ xv, const float* __restrict__ Wq,
    const float* __restrict__ Wk, const float* __restrict__ Wv,
    const float* __restrict__ Wo, bf16* __restrict__ xqo,
    bf16* __restrict__ xko, bf16* __restrict__ xvo, bf16* __restrict__ Wqo,
    bf16* __restrict__ Wko, bf16* __restrict__ Wvo, bf16* __restrict__ Woo) {
    const int y = blockIdx.y;
    const float* src;
    bf16* dst;
    size_t n;
    const size_t NX = (size_t)BB * SS * EMBD;    // 4 Mi
    const size_t NW = (size_t)EMBD * EMBD;       // 1 Mi
    switch (y) {
        case 0: src = xq; dst = xqo; n = NX; break;
        case 1: src = xk; dst = xko; n = NX; break;
        case 2: src = xv; dst = xvo; n = NX; break;
        case 3: src = Wq; dst = Wqo; n = NW; break;
        case 4: src = Wk; dst = Wko; n = NW; break;
        case 5: src = Wv; dst = Wvo; n = NW; break;
        default: src = Wo; dst = Woo; n = NW; break;
    }
    const size_t stride = (size_t)gridDim.x * blockDim.x * 4;
    for (size_t i = ((size_t)blockIdx.x * blockDim.x + threadIdx.x) * 4;
         i < n; i += stride) {
        floatx4 v = *(const floatx4*)(src + i);
        bf16x4 o = {(bf16)v[0], (bf16)v[1], (bf16)v[2], (bf16)v[3]};
        *(bf16x4*)(dst + i) = o;
    }
}

// ---------------------------------------------------------------------------
// GEMM (unchanged from R9): dynamic LDS, BK=64 staged as two packed 32-col
// halves, per-wave LDS repack epilogue.
// ---------------------------------------------------------------------------
extern __shared__ __align__(16) char smem[];

template <int MODE, int FM>
__device__ __forceinline__ void gemm_body(const bf16* __restrict__ A,
                                          const bf16* __restrict__ W,
                                          const float* __restrict__ bias,
                                          void* __restrict__ Ov,
                                          int mBase, int nBase, float oscale) {
    constexpr int BM = 32 * FM;
    constexpr int ABYTES = BM * 64 * 2;
    bf16* As = (bf16*)smem;
    bf16* Bs = (bf16*)(smem + ABYTES);

    const int t = threadIdx.x;
    const int l = t & 63, w = t >> 6;
    const int lm = l & 15, lq = l >> 4;
    const int K = 1024;
    const int wm = (w >> 1) * (16 * FM), wn = (w & 1) * 64;

    const floatx4 zero = {0.f, 0.f, 0.f, 0.f};
    floatx4 acc[FM][4];
#pragma unroll
    for (int i = 0; i < FM; i++)
#pragma unroll
        for (int j = 0; j < 4; j++) acc[i][j] = zero;

    for (int kb = 0; kb < K; kb += 64) {
        __syncthreads();
#pragma unroll
        for (int ia = 0; ia < FM; ia++) {
            int half = ia / (FM / 2 > 0 ? FM / 2 : 1);
            int rem  = (ia % (FM / 2 > 0 ? FM / 2 : 1)) * 256 + t;
            int row  = rem >> 2;
            int col  = half * 32 + (rem & 3) * 8;
            gl_lds16(A + (size_t)(mBase + row) * K + kb + col,
                     (char*)As + (ia * 256 + w * 64) * 16);
        }
#pragma unroll
        for (int i = 0; i < 4; i++) {
            int half = i >> 1;
            int rem  = (i & 1) * 256 + t;
            int row  = rem >> 2;
            int col  = half * 32 + (rem & 3) * 8;
            gl_lds16(W + (size_t)(nBase + row) * K + kb + col,
                     (char*)Bs + (i * 256 + w * 64) * 16);
        }
        __syncthreads();

#pragma unroll
        for (int half = 0; half < 2; half++) {
            const bf16* Ah = As + half * BM * 32;
            const bf16* Bh = Bs + half * 128 * 32;
            bf16x8 af[FM], bfv[4];
#pragma unroll
            for (int f = 0; f < FM; f++)
                af[f] = *(const bf16x8*)&Ah[(wm + f * 16 + lm) * 32 + lq * 8];
#pragma unroll
            for (int f = 0; f < 4; f++)
                bfv[f] = *(const bf16x8*)&Bh[(wn + f * 16 + lm) * 32 + lq * 8];
            if (MODE == 2) {
#pragma unroll
                for (int i = 0; i < 4; i++)
#pragma unroll
                    for (int j = 0; j < FM; j++)
                        acc[j][i] = __builtin_amdgcn_mfma_f32_16x16x32_bf16(
                            bfv[i], af[j], acc[j][i], 0, 0, 0);
            } else {
#pragma unroll
                for (int fm = 0; fm < FM; fm++)
#pragma unroll
                    for (int fn = 0; fn < 4; fn++)
                        acc[fm][fn] =
                            __builtin_amdgcn_mfma_f32_16x16x32_bf16(
                                af[fm], bfv[fn], acc[fm][fn], 0, 0, 0);
            }
        }
    }

    __syncthreads();
    float* rp = (float*)smem + w * (16 * 68);

    if (MODE != 2) {
        float bvv[4];
#pragma unroll
        for (int fn = 0; fn < 4; fn++)
            bvv[fn] = bias[nBase + wn + fn * 16 + lm];
#pragma unroll
        for (int fm = 0; fm < FM; fm++) {
#pragma unroll
            for (int fn = 0; fn < 4; fn++)
#pragma unroll
                for (int r = 0; r < 4; r++)
                    rp[(lq * 4 + r) * 68 + fn * 16 + lm] =
                        (acc[fm][fn][r] + bvv[fn]) * oscale;
            if (MODE == 0) {
                int row2 = l >> 3, col8 = l & 7;
                int h = (nBase + wn) >> 6;
#pragma unroll
                for (int p = 0; p < 2; p++) {
                    int row = p * 8 + row2;
                    int m = mBase + wm + fm * 16 + row;
                    int b = m >> 11, s = m & 2047;
                    bf16x8 o = cvt8(&rp[row * 68 + col8 * 8]);
                    *(bf16x8*)((bf16*)Ov +
                               (((size_t)(b * NH + h)) * SS + s) * HD +
                               col8 * 8) = o;
                }
            } else {
                int c4 = l & 15;
#pragma unroll
                for (int p = 0; p < 4; p++) {
                    int row = p * 4 + (l >> 4);
                    int m = mBase + wm + fm * 16 + row;
                    floatx4 o = *(const floatx4*)&rp[row * 68 + c4 * 4];
                    *(floatx4*)((float*)Ov + (size_t)m * EMBD + nBase + wn +
                                c4 * 4) = o;
                }
            }
        }
    } else {
        const int b = (mBase + wm) >> 11;
        const int sbase = (mBase + wm) & 2047;
#pragma unroll
        for (int i = 0; i < 4; i++) {
            float bv[4];
#pragma unroll
            for (int r = 0; r < 4; r++)
                bv[r] = bias[nBase + wn + i * 16 + lq * 4 + r];
#pragma unroll
            for (int j = 0; j < FM; j++)
#pragma unroll
                for (int r = 0; r < 4; r++)
                    rp[(lq * 4 + r) * 68 + j * 16 + lm] =
                        acc[j][i][r] + bv[r];
            int row2 = l >> 3, col8 = l & 7;
#pragma unroll
            for (int p = 0; p < 2; p++) {
                int row = p * 8 + row2;
                int n = nBase + wn + i * 16 + row;
                int h = n >> 6, d = n & 63;
                bf16x8 o = cvt8(&rp[row * 68 + col8 * 8]);
                *(bf16x8*)((bf16*)Ov +
                           ((size_t)(b * NH + h) * HD + d) * SS + sbase +
                           col8 * 8) = o;
            }
        }
    }
}

__global__ __launch_bounds__(256, 4) void gemm_qkv(
    const bf16* __restrict__ xq, const bf16* __restrict__ xk,
    const bf16* __restrict__ xv, const bf16* __restrict__ Wq,
    const bf16* __restrict__ Wk, const bf16* __restrict__ Wv,
    const float* __restrict__ bq, const float* __restrict__ bk,
    const float* __restrict__ bv, bf16* __restrict__ Qo,
    bf16* __restrict__ Ko, bf16* __restrict__ Vo) {
    const int z = blockIdx.z;
    const int mB = blockIdx.x * 128, nB = blockIdx.y * 128;
    if (z == 0)
        gemm_body<0, 4>(xq, Wq, bq, Qo, mB, nB, QSCALE);
    else if (z == 1)
        gemm_body<0, 4>(xk, Wk, bk, Ko, mB, nB, 1.0f);
    else
        gemm_body<2, 4>(xv, Wv, bv, Vo, mB, nB, 1.0f);
}

__global__ __launch_bounds__(256, 4) void gemm_out(
    const bf16* __restrict__ A, const bf16* __restrict__ W,
    const float* __restrict__ bias, float* __restrict__ O) {
    gemm_body<1, 2>(A, W, bias, O, blockIdx.x * 64, blockIdx.y * 128, 1.0f);
}

// ---------------------------------------------------------------------------
// Flash attention, KT=128: two 64-key sub-tiles per barrier pair -> half the
// per-tile softmax overhead (reductions, alpha, od-rescale) and half the
// barrier drains per key; 32 MFMA per chunk. Raw v_exp_f32 via
// __builtin_amdgcn_exp2f. Last chunk masks key > qglob (diagonal + overhang).
// LDS 53 KB -> 3 blocks/CU. Grid 1024, longest-first, XCD-pinned.
// ---------------------------------------------------------------------------
__global__ __launch_bounds__(256, 3) void attn_fwd(
    const bf16* __restrict__ Qg, const bf16* __restrict__ Kg,
    const bf16* __restrict__ Vtg, bf16* __restrict__ Oatt) {
    __shared__ __align__(16) bf16 Ks[128 * 72];      // [key][d], padded
    __shared__ __align__(16) bf16 VT[64 * 136];      // [d][key], padded
    __shared__ __align__(16) bf16 Ps[4][16 * 136];   // per-wave P [q][key]

    const int t = threadIdx.x;
    const int l = t & 63, w = t >> 6;
    const int lm = l & 15, lq = l >> 4;
    const int x = blockIdx.x;
    const int qt = 31 - (x >> 5);              // longest jobs first
    const int bh = (((x >> 3) & 3) << 3) | (x & 7);  // XCD-pinned head
    const int nch = (qt >> 1) + 1;             // 128-key chunks
    const size_t kbase = (size_t)bh * SS * HD;
    const size_t vbase = (size_t)bh * HD * SS;
    const int b = bh >> 4, h = bh & 15;
    const floatx4 zero = {0.f, 0.f, 0.f, 0.f};

    bf16x8 qa0, qa1;
    {
        const bf16* qp =
            Qg + kbase + (size_t)(qt * 64 + w * 16 + lm) * HD + lq * 8;
        qa0 = *(const bf16x8*)qp;
        qa1 = *(const bf16x8*)(qp + 32);
    }

    float m_i = NEG_BIG, l_i = 0.f;            // stats for q = lm (this wave)
    floatx4 od[4];
#pragma unroll
    for (int dt = 0; dt < 4; dt++) od[dt] = zero;

    const int qglob = qt * 64 + w * 16 + lm;

    // Prefetch chunk 0: K rows 0..127, V^T keys 0..127.
    bf16x8 kreg[4], vreg[4];
#pragma unroll
    for (int i = 0; i < 4; i++) {
        int idx = i * 256 + t;                 // 0..1023
        int rowK = idx >> 3, colK = (idx & 7) * 8;
        kreg[i] = *(const bf16x8*)(Kg + kbase + (size_t)rowK * HD + colK);
        int dV = idx >> 4, keyb = (idx & 15) * 8;
        vreg[i] = *(const bf16x8*)(Vtg + vbase + (size_t)dV * SS + keyb);
    }

    for (int kt = 0; kt < nch; ++kt) {
        __syncthreads();
#pragma unroll
        for (int i = 0; i < 4; i++) {
            int idx = i * 256 + t;
            int rowK = idx >> 3, colK = (idx & 7) * 8;
            *(bf16x8*)&Ks[rowK * 72 + colK] = kreg[i];
            int dV = idx >> 4, keyb = (idx & 15) * 8;
            *(bf16x8*)&VT[dV * 136 + keyb] = vreg[i];
        }
        __syncthreads();
        if (kt < nch - 1) {
#pragma unroll
            for (int i = 0; i < 4; i++) {
                int idx = i * 256 + t;
                int rowK = idx >> 3, colK = (idx & 7) * 8;
                kreg[i] = *(const bf16x8*)(
                    Kg + kbase + (size_t)((kt + 1) * 128 + rowK) * HD + colK);
                int dV = idx >> 4, keyb = (idx & 15) * 8;
                vreg[i] = *(const bf16x8*)(
                    Vtg + vbase + (size_t)dV * SS + (kt + 1) * 128 + keyb);
            }
        }

        // S^T[key][q], 8 subtiles of 16 keys (128 total)
        floatx4 sc[8];
#pragma unroll
        for (int j0 = 0; j0 < 8; j0++) {
            int rowK = j0 * 16 + lm;
            bf16x8 k0 = *(const bf16x8*)&Ks[rowK * 72 + lq * 8];
            bf16x8 k1 = *(const bf16x8*)&Ks[rowK * 72 + 32 + lq * 8];
            floatx4 z = zero;
            z = __builtin_amdgcn_mfma_f32_16x16x32_bf16(k0, qa0, z, 0, 0, 0);
            z = __builtin_amdgcn_mfma_f32_16x16x32_bf16(k1, qa1, z, 0, 0, 0);
            sc[j0] = z;
        }
        if (kt == nch - 1) {  // causal mask: diagonal + 64-key overhang
#pragma unroll
            for (int j0 = 0; j0 < 8; j0++)
#pragma unroll
                for (int r = 0; r < 4; r++) {
                    int key = kt * 128 + j0 * 16 + lq * 4 + r;
                    if (key > qglob) sc[j0][r] = NEG_BIG;
                }
        }
        // Online softmax (exp2 domain); all 32 regs belong to q = lm.
        float mt = sc[0][0];
#pragma unroll
        for (int j0 = 0; j0 < 8; j0++)
#pragma unroll
            for (int r = 0; r < 4; r++) mt = fmaxf(mt, sc[j0][r]);
        mt = fmaxf(mt, __shfl_xor(mt, 16));
        mt = fmaxf(mt, __shfl_xor(mt, 32));
        float mnew = fmaxf(m_i, mt);
        float alpha = __builtin_amdgcn_exp2f(m_i - mnew);
        m_i = mnew;
        float ps = 0.f;
#pragma unroll
        for (int j0 = 0; j0 < 8; j0++)
#pragma unroll
            for (int r = 0; r < 4; r++) {
                float p = __builtin_amdgcn_exp2f(sc[j0][r] - mnew);
                sc[j0][r] = p;
                ps += p;
            }
        ps += __shfl_xor(ps, 16);
        ps += __shfl_xor(ps, 32);
        l_i = l_i * alpha + ps;
#pragma unroll
        for (int j0 = 0; j0 < 8; j0++) {
            bf16x4 pk = {(bf16)sc[j0][0], (bf16)sc[j0][1], (bf16)sc[j0][2],
                         (bf16)sc[j0][3]};
            *(bf16x4*)&Ps[w][lm * 136 + j0 * 16 + lq * 4] = pk;
        }
        float a0 = __shfl(alpha, lq * 4 + 0);
        float a1 = __shfl(alpha, lq * 4 + 1);
        float a2 = __shfl(alpha, lq * 4 + 2);
        float a3 = __shfl(alpha, lq * 4 + 3);
#pragma unroll
        for (int dt = 0; dt < 4; dt++) {
            od[dt][0] *= a0;
            od[dt][1] *= a1;
            od[dt][2] *= a2;
            od[dt][3] *= a3;
        }
        // PV over 128 keys = 4 k-steps; A-frags shared across dt.
        bf16x8 pa[4];
#pragma unroll
        for (int s = 0; s < 4; s++)
            pa[s] = *(const bf16x8*)&Ps[w][lm * 136 + s * 32 + lq * 8];
#pragma unroll
        for (int dt = 0; dt < 4; dt++) {
            int rowD = dt * 16 + lm;
#pragma unroll
            for (int s = 0; s < 4; s++) {
                bf16x8 v = *(const bf16x8*)&VT[rowD * 136 + s * 32 + lq * 8];
                od[dt] = __builtin_amdgcn_mfma_f32_16x16x32_bf16(pa[s], v,
                                                                 od[dt], 0, 0,
                                                                 0);
            }
        }
    }

    float linv = 1.0f / l_i;
    float lr0 = __shfl(linv, lq * 4 + 0);
    float lr1 = __shfl(linv, lq * 4 + 1);
    float lr2 = __shfl(linv, lq * 4 + 2);
    float lr3 = __shfl(linv, lq * 4 + 3);
    float lr[4] = {lr0, lr1, lr2, lr3};
#pragma unroll
    for (int dt = 0; dt < 4; dt++) {
#pragma unroll
        for (int r = 0; r < 4; r++) {
            int s = qt * 64 + w * 16 + lq * 4 + r;
            float v = od[dt][r] * lr[r];
            Oatt[((size_t)(b * SS + s)) * EMBD + h * HD + dt * 16 + lm] =
                (bf16)v;
        }
    }
}

// ---------------------------------------------------------------------------
extern "C" void kernel_launch(void* const* d_in, const int* in_sizes, int n_in,
                              void* d_out, int out_size, void* d_ws,
                              size_t ws_size, hipStream_t stream) {
    const float* xq = (const float*)d_in[0];
    const float* xk = (const float*)d_in[1];
    const float* xv = (const float*)d_in[2];
    // d_in[3] = causal mask — hard-coded
    const float* Wq = (const float*)d_in[4];
    const float* bq = (const float*)d_in[5];
    const float* Wk = (const float*)d_in[6];
    const float* bk = (const float*)d_in[7];
    const float* Wv = (const float*)d_in[8];
    const float* bv = (const float*)d_in[9];
    const float* Wo = (const float*)d_in[10];
    const float* bo = (const float*)d_in[11];
    float* out = (float*)d_out;

    const size_t NX = (size_t)BB * SS * EMBD;
    const size_t NW = (size_t)EMBD * EMBD;
    bf16* Qw  = (bf16*)d_ws;        // [B,H,S,D], pre-scaled
    bf16* Kw  = Qw + NX;            // [B,H,S,D]
    bf16* Vw  = Kw + NX;            // [B,H,D,S]
    bf16* Aw  = Vw + NX;            // [B,S,E]
    bf16* xqb = Aw + NX;
    bf16* xkb = xqb + NX;
    bf16* xvb = xkb + NX;
    bf16* Wqb = xvb + NX;
    bf16* Wkb = Wqb + NW;
    bf16* Wvb = Wkb + NW;
    bf16* Wob = Wvb + NW;

    cvt_all<<<dim3(1024, 7), 256, 0, stream>>>(xq, xk, xv, Wq, Wk, Wv, Wo,
                                               xqb, xkb, xvb, Wqb, Wkb, Wvb,
                                               Wob);
    gemm_qkv<<<dim3(32, 8, 3), 256, 32768, stream>>>(
        xqb, xkb, xvb, Wqb, Wkb, Wvb, bq, bk, bv, Qw, Kw, Vw);
    attn_fwd<<<dim3(1024), 256, 0, stream>>>(Qw, Kw, Vw, Aw);
    gemm_out<<<dim3(64, 8), 256, 24576, stream>>>(Aw, Wob, bo, out);
}